// Round 16
// baseline (28.206 us; speedup 1.0000x reference)
//
#include <hip/hip_runtime.h>

// LIF scan, x (B=32,G=4,T=512,C=256) f32 -> 32768 chains, T sequential.
// Memory-bound: 67 MB R + 67 MB W.
//
// R16 = R15 (25.6us) + ONE change: per-consumer-wave x4 nt stores.
//  Consumers stage 4 steps x 64 ch in a private 1KB LDS buffer (stride-1
//  ds_write; ds_read_b128 back at 2-way aliasing = free), then issue ONE
//  nontemporal global_store_dwordx4 per 4 steps: store instrs 512 -> 128
//  per wave. Within-wave only (lgkmcnt), no extra barriers (R8/R9 trap).
//  - Block = sequence n: 320 threads = 1 producer wave + 4 consumer waves.
//  - Producer: pure global_load_lds_dwordx4 (1 KiB contiguous row per instr)
//    into a K=4-window LDS ring (16 rows/window, 64 KiB). Counted vmcnt(32)
//    per window (W+1,W+2 stay in flight across barriers - T4 discipline).
//  - Consumers: ch = wave*64+lane; scan from LDS (stride-1 ds_read,
//    conflict-free), x4 nontemporal stores via private staging buffer.
//  - Recurrence bit-exact: contract off, v=(w*xt)+(a*Vm); Vm'=(Vm-1>=0)?0:v.

typedef float f32x4 __attribute__((ext_vector_type(4)));

constexpr int T_STEPS = 512;
constexpr int CCH     = 256;
constexpr int NSEQ    = 128;
constexpr int WIN     = 16;              // rows per window
constexpr int K       = 4;               // ring depth (windows)
constexpr int NW      = T_STEPS / WIN;   // 32

__device__ __forceinline__ void sfence() { __builtin_amdgcn_sched_barrier(0); }

__global__ __launch_bounds__(320, 1) void lif_kernel(
    const float* __restrict__ x,
    const float* __restrict__ w_input,
    const float* __restrict__ w_leak,
    float* __restrict__ out)
{
#pragma clang fp contract(off)
    __shared__ float xw[K][WIN * CCH];   // 4 x 16 KiB window ring
    __shared__ float obuf[4][4 * 64];    // per-consumer-wave 1 KB staging

    const int tid  = threadIdx.x;
    const int wv   = tid >> 6;           // 0..3 consumers, 4 producer
    const int lane = tid & 63;
    const int n    = blockIdx.x;

    if (wv == 4) {
        // ---- producer wave: pure load queue ----
        const float* xg = x + (size_t)n * T_STEPS * CCH + lane * 4;
        auto issue = [&](int W) {
            const float* s0 = xg + (size_t)W * WIN * CCH;
            float* d0 = &xw[W & 3][0];
#pragma unroll
            for (int i = 0; i < WIN; ++i) {
                // one instr = one contiguous 1 KiB row t = W*16+i
                __builtin_amdgcn_global_load_lds(
                    (const __attribute__((address_space(1))) void*)(s0 + i * CCH),
                    (__attribute__((address_space(3))) void*)(d0 + i * CCH),
                    16, 0, 0);
            }
            sfence();
        };

        issue(0); issue(1); issue(2);    // 48 outstanding (< 63 cap)
        for (int W = 0; W < NW; ++W) {
            const int rem = NW - 1 - W;  // windows still outstanding after W
            if (rem >= 2)      asm volatile("s_waitcnt vmcnt(32)" ::: "memory");
            else if (rem == 1) asm volatile("s_waitcnt vmcnt(16)" ::: "memory");
            else               asm volatile("s_waitcnt vmcnt(0)"  ::: "memory");
            sfence();
            __builtin_amdgcn_s_barrier();   // window W now readable
            sfence();
            if (W + 3 < NW) issue(W + 3);   // into slot consumers freed at W-1
        }
    } else {
        // ---- consumer waves: scan + staged x4 nontemporal store queue ----
        const int ch = wv * 64 + lane;
        const float w = w_input[ch];
        const float a = 1.0f - w_leak[ch];
        // x4 store base: lane i covers row-offset (i>>4), cols 4*(i&15)..+3
        // within this wave's 64-channel span.
        float* og = out + (size_t)n * T_STEPS * CCH
                        + wv * 64 + 4 * (lane & 15) + (size_t)(lane >> 4) * CCH;
        float* st = &obuf[wv][0];
        float Vm = 0.0f;

        for (int W = 0; W < NW; ++W) {
            sfence();
            __builtin_amdgcn_s_barrier();   // window W ready in LDS
            sfence();
            const float* xb = &xw[W & 3][0];
#pragma unroll
            for (int k = 0; k < WIN; ++k) {
                const float xt = xb[k * CCH + ch];       // stride-1, no conflict
                // exact numpy op order: mul, mul, add (no FMA), spike gate
                const float v = (w * xt) + (a * Vm);
                Vm = (Vm - 1.0f >= 0.0f) ? 0.0f : v;
                st[(k & 3) * 64 + lane] = Vm;            // stride-1 ds_write
                if ((k & 3) == 3) {
                    // read back 16B/lane (2-way bank alias = free), one x4 nt
                    // store covers rows W*16+(k-3)..+3 of the wave's span
                    const f32x4 vv =
                        *(const f32x4*)&st[(lane >> 4) * 64 + 4 * (lane & 15)];
                    __builtin_nontemporal_store(
                        vv, (f32x4*)(og + (size_t)(W * WIN + (k - 3)) * CCH));
                }
            }
            sfence();
        }
    }
}

extern "C" void kernel_launch(void* const* d_in, const int* in_sizes, int n_in,
                              void* d_out, int out_size, void* d_ws, size_t ws_size,
                              hipStream_t stream) {
    const float* x       = (const float*)d_in[0];
    const float* w_input = (const float*)d_in[1];
    const float* w_leak  = (const float*)d_in[2];
    float* out = (float*)d_out;

    dim3 grid(NSEQ);       // 128 blocks, block n = sequence n
    dim3 block(320);       // 4 consumer waves + 1 producer wave
    hipLaunchKernelGGL(lif_kernel, grid, block, 0, stream,
                       x, w_input, w_leak, out);
}

// Round 17
// 25.926 us; speedup vs baseline: 1.0879x; 1.0879x over previous
//
#include <hip/hip_runtime.h>

// LIF scan, x (B=32,G=4,T=512,C=256) f32 -> 32768 chains, T sequential.
// Memory-bound: 67 MB R + 67 MB W.
//
// FINAL (= R15, best of 16 rounds: 25.6 us = 5.23 TB/s = 83% of the 6.29
// TB/s copy ceiling; serial-scan structural floor ~21.3 us).
//  - Block = sequence n: 320 threads = 1 producer wave + 4 consumer waves
//    (producer/consumer split: separate load queue from store queue, +0.9us).
//  - Producer: pure global_load_lds_dwordx4 (1 KiB contiguous row per instr)
//    into a K=4-window LDS ring (16 rows/window, 64 KiB). Counted vmcnt(32)
//    per window - W+1, W+2 stay in flight across barriers (T4 discipline).
//  - Consumers: ch = wave*64+lane; scan from LDS (stride-1 ds_read,
//    conflict-free), free-running NONTEMPORAL scalar stores (+0.5us: out
//    stream bypasses L3, keeping x L3-resident).
//  - 5 waves/CU on 128 CUs: TLP covers chunk-boundary stalls (+1.0us vs 1/CU).
//  - Verified-negative alternatives: barrier-paced staging (R8/R9), x4 store
//    widening via LDS round-trip (R16), deeper queues (R5/R14), 256 CUs
//    (R11/R14), 1 KiB store instrs (R10).
//  - Recurrence bit-exact vs numpy ref: contract off, v=(w*xt)+(a*Vm);
//    Vm'=(Vm-1>=0)?0:v  (R={0,1} exact algebra eliminates the R-state).

constexpr int T_STEPS = 512;
constexpr int CCH     = 256;
constexpr int NSEQ    = 128;
constexpr int WIN     = 16;              // rows per window
constexpr int K       = 4;               // ring depth (windows)
constexpr int NW      = T_STEPS / WIN;   // 32

__device__ __forceinline__ void sfence() { __builtin_amdgcn_sched_barrier(0); }

__global__ __launch_bounds__(320, 1) void lif_kernel(
    const float* __restrict__ x,
    const float* __restrict__ w_input,
    const float* __restrict__ w_leak,
    float* __restrict__ out)
{
#pragma clang fp contract(off)
    __shared__ float xw[K][WIN * CCH];   // 4 x 16 KiB window ring

    const int tid  = threadIdx.x;
    const int wv   = tid >> 6;           // 0..3 consumers, 4 producer
    const int lane = tid & 63;
    const int n    = blockIdx.x;

    if (wv == 4) {
        // ---- producer wave: pure load queue ----
        const float* xg = x + (size_t)n * T_STEPS * CCH + lane * 4;
        auto issue = [&](int W) {
            const float* s0 = xg + (size_t)W * WIN * CCH;
            float* d0 = &xw[W & 3][0];
#pragma unroll
            for (int i = 0; i < WIN; ++i) {
                // one instr = one contiguous 1 KiB row t = W*16+i
                __builtin_amdgcn_global_load_lds(
                    (const __attribute__((address_space(1))) void*)(s0 + i * CCH),
                    (__attribute__((address_space(3))) void*)(d0 + i * CCH),
                    16, 0, 0);
            }
            sfence();
        };

        issue(0); issue(1); issue(2);    // 48 outstanding (< 63 cap)
        for (int W = 0; W < NW; ++W) {
            const int rem = NW - 1 - W;  // windows still outstanding after W
            if (rem >= 2)      asm volatile("s_waitcnt vmcnt(32)" ::: "memory");
            else if (rem == 1) asm volatile("s_waitcnt vmcnt(16)" ::: "memory");
            else               asm volatile("s_waitcnt vmcnt(0)"  ::: "memory");
            sfence();
            __builtin_amdgcn_s_barrier();   // window W now readable
            sfence();
            if (W + 3 < NW) issue(W + 3);   // into slot consumers freed at W-1
        }
    } else {
        // ---- consumer waves: scan + pure store queue (nontemporal) ----
        const int ch = wv * 64 + lane;
        const float w = w_input[ch];
        const float a = 1.0f - w_leak[ch];
        float* og = out + (size_t)n * T_STEPS * CCH + ch;
        float Vm = 0.0f;

        for (int W = 0; W < NW; ++W) {
            sfence();
            __builtin_amdgcn_s_barrier();   // window W ready in LDS
            sfence();
            const float* xb = &xw[W & 3][0];
#pragma unroll
            for (int k = 0; k < WIN; ++k) {
                const float xt = xb[k * CCH + ch];       // stride-1, no conflict
                // exact numpy op order: mul, mul, add (no FMA), spike gate
                const float v = (w * xt) + (a * Vm);
                Vm = (Vm - 1.0f >= 0.0f) ? 0.0f : v;
                __builtin_nontemporal_store(
                    Vm, og + (size_t)(W * WIN + k) * CCH);  // stream past L3
            }
            sfence();
        }
    }
}

extern "C" void kernel_launch(void* const* d_in, const int* in_sizes, int n_in,
                              void* d_out, int out_size, void* d_ws, size_t ws_size,
                              hipStream_t stream) {
    const float* x       = (const float*)d_in[0];
    const float* w_input = (const float*)d_in[1];
    const float* w_leak  = (const float*)d_in[2];
    float* out = (float*)d_out;

    dim3 grid(NSEQ);       // 128 blocks, block n = sequence n
    dim3 block(320);       // 4 consumer waves + 1 producer wave
    hipLaunchKernelGGL(lif_kernel, grid, block, 0, stream,
                       x, w_input, w_leak, out);
}